// Round 2
// baseline (348.156 us; speedup 1.0000x reference)
//
#include <hip/hip_runtime.h>
#include <hip/hip_bf16.h>

// ---------------------------------------------------------------------------
// MultiHeadAttention fused kernel for MI355X (gfx950)
// B=8 S=4096 Q=32 H=8 D=64 IN=512 NKV=1024
// Structure: detect dtype -> q projection -> fused (KV-proj + attention
// partial sums via atomics) -> divide.
// ---------------------------------------------------------------------------

typedef float f32x4 __attribute__((ext_vector_type(4)));
typedef short s16x8 __attribute__((ext_vector_type(8)));

__device__ __forceinline__ unsigned short f2bf(float f) {
  union { __hip_bfloat16 h; unsigned short u; } cv;
  cv.h = __float2bfloat16(f);
  return cv.u;
}
__device__ __forceinline__ float bf2f(unsigned short u) {
  union { unsigned short u; __hip_bfloat16 h; } cv;
  cv.u = u;
  return __bfloat162float(cv.h);
}
__device__ __forceinline__ float tofl(float v) { return v; }
__device__ __forceinline__ float tofl(__hip_bfloat16 v) { return __bfloat162float(v); }

__device__ __forceinline__ f32x4 mfma16(s16x8 a, s16x8 b, f32x4 c) {
  return __builtin_amdgcn_mfma_f32_16x16x32_bf16(a, b, c, 0, 0, 0);
}

// stage 16 contiguous elements (along K) from global into LDS as bf16
__device__ __forceinline__ void stage16(unsigned short* dst, const float* src) {
  const float4* s4 = reinterpret_cast<const float4*>(src);
  float4 f0 = s4[0], f1 = s4[1], f2 = s4[2], f3 = s4[3];
  union { unsigned short u[16]; s16x8 v[2]; } t;
  t.u[0] = f2bf(f0.x);  t.u[1] = f2bf(f0.y);  t.u[2] = f2bf(f0.z);  t.u[3] = f2bf(f0.w);
  t.u[4] = f2bf(f1.x);  t.u[5] = f2bf(f1.y);  t.u[6] = f2bf(f1.z);  t.u[7] = f2bf(f1.w);
  t.u[8] = f2bf(f2.x);  t.u[9] = f2bf(f2.y);  t.u[10] = f2bf(f2.z); t.u[11] = f2bf(f2.w);
  t.u[12] = f2bf(f3.x); t.u[13] = f2bf(f3.y); t.u[14] = f2bf(f3.z); t.u[15] = f2bf(f3.w);
  s16x8* d8 = reinterpret_cast<s16x8*>(dst);
  d8[0] = t.v[0];
  d8[1] = t.v[1];
}
__device__ __forceinline__ void stage16(unsigned short* dst, const __hip_bfloat16* src) {
  const s16x8* s8 = reinterpret_cast<const s16x8*>(src);
  s16x8 a = s8[0], b = s8[1];
  s16x8* d8 = reinterpret_cast<s16x8*>(dst);
  d8[0] = a;
  d8[1] = b;
}

// ---------------------------------------------------------------------------
// dtype detection (FIXED endianness): test EVEN u16 entries.
//  - bf16 array: even entries are real bf16 elements -> plausible exponent
//    (~100% for N(0,1) data).
//  - fp32 array (little-endian): even entries are the LOW mantissa halves ->
//    exponent field is ~uniform-random -> ~12% plausible.
// (Odd entries are useless: for fp32 they're the HIGH halves, which look
//  exactly like truncated bf16 — that was the round-1 NaN bug.)
// flag: 1 = fp32, 0 = bf16.
// ---------------------------------------------------------------------------
__global__ void k_detect(const unsigned short* __restrict__ in16, int* __restrict__ flag) {
  __shared__ int cnt;
  int t = threadIdx.x;
  if (t == 0) cnt = 0;
  __syncthreads();
  unsigned short v = in16[2 * t];  // EVEN entries
  int e = (v >> 7) & 0xFF;
  int ok = (e >= 100 && e <= 130) ? 1 : 0;
  atomicAdd(&cnt, ok);
  __syncthreads();
  if (t == 0) *flag = (cnt >= 128) ? 0 : 1;
}

// ---------------------------------------------------------------------------
// q projection: q[b,qi,:] = queries[b,qi,:] @ Wq.T + bq  -> bf16 in ws
// 128 blocks x 256 thr; block handles 2 rows (of 256), thread 2 cols.
// ---------------------------------------------------------------------------
template <typename T>
__device__ __forceinline__ void qproj_body(const T* __restrict__ queries,
                                           const T* __restrict__ Wq,
                                           const T* __restrict__ bq,
                                           unsigned short* __restrict__ qws,
                                           float* qrow /* 2*512 LDS */) {
  const int r0 = blockIdx.x * 2;
  const int t = threadIdx.x;
  for (int i = t; i < 1024; i += 256)
    qrow[i] = tofl(queries[(size_t)r0 * 512 + i]);
  __syncthreads();
  for (int cc = 0; cc < 2; ++cc) {
    int c = t + cc * 256;
    float a0 = 0.f, a1 = 0.f;
    const T* wrow = Wq + (size_t)c * 512;
    for (int k = 0; k < 512; ++k) {
      float wv = tofl(wrow[k]);
      a0 += qrow[k] * wv;
      a1 += qrow[512 + k] * wv;
    }
    float bb = tofl(bq[c]);
    qws[(size_t)r0 * 512 + c] = f2bf(a0 + bb);
    qws[(size_t)(r0 + 1) * 512 + c] = f2bf(a1 + bb);
  }
}

__global__ __launch_bounds__(256) void k_qproj(const void* queries, const void* Wq,
                                               const void* bq, unsigned short* qws,
                                               const int* __restrict__ flag) {
  __shared__ float qrow[2 * 512];
  if (*flag == 1)
    qproj_body<float>((const float*)queries, (const float*)Wq, (const float*)bq, qws, qrow);
  else
    qproj_body<__hip_bfloat16>((const __hip_bfloat16*)queries, (const __hip_bfloat16*)Wq,
                               (const __hip_bfloat16*)bq, qws, qrow);
}

// ---------------------------------------------------------------------------
// Fused kernel. Grid (32 s-tiles, 8 batches, 4 head-pairs), 256 threads.
// Per block: two 128x128x512 bf16-MFMA sub-GEMMs (K cols then V cols of the
// head-pair), u-GEMM (q.kT), P = exp(clip(elu(u/sqrt512)))*mask, num-GEMM
// (P.V), atomic accumulation of num/den across the 32 s-tile blocks.
// MFMA 16x16x32_bf16 layouts (HW-verified per guide):
//   A: m=lane&15, k=quad*8+j ; B: n=lane&15, k=quad*8+j ;
//   D: col=lane&15, row=quad*4+reg
// ---------------------------------------------------------------------------
template <typename T>
__device__ __forceinline__ void fused_body(
    const T* __restrict__ inputs, const T* __restrict__ masks,
    const T* __restrict__ Wkv, const T* __restrict__ bkv,
    const unsigned short* __restrict__ qws,
    float* __restrict__ num, float* __restrict__ den,
    unsigned short* Abuf, unsigned short* Bbuf,
    unsigned short* kvbuf, unsigned short* Pbuf) {
  const int stile = blockIdx.x;  // 0..31
  const int b = blockIdx.y;      // 0..7
  const int hp = blockIdx.z;     // 0..3  (head pair: heads 2hp, 2hp+1)
  const int s0 = stile * 128;
  const int tid = threadIdx.x;
  const int w = tid >> 6;
  const int l = tid & 63;
  const int quad = l >> 4;
  const int l16 = l & 15;
  const int wr = (w >> 1) * 64;  // wave row block in 128x128 tile
  const int wc = (w & 1) * 64;   // wave col block
  const int hh = w >> 1;         // head-in-pair for u/num GEMMs
  const int mt = w & 1;          // q-row tile (16) for u/num GEMMs

  const int r_st = tid >> 1;          // staging row 0..127
  const int kk_st = (tid & 1) * 16;   // staging k offset 0/16
  const T* Asrc = inputs + ((size_t)(b * 4096 + s0 + r_st)) * 512 + kk_st;

  const f32x4 zero4 = {0.f, 0.f, 0.f, 0.f};

  for (int phase = 0; phase < 2; ++phase) {
    const int nc0 = phase * 512 + hp * 128;  // kv column base (K cols then V cols)
    f32x4 acc[4][4];
#pragma unroll
    for (int i = 0; i < 4; ++i)
#pragma unroll
      for (int j = 0; j < 4; ++j) acc[i][j] = zero4;

    const T* Bsrc = Wkv + ((size_t)(nc0 + r_st)) * 512 + kk_st;

    for (int k0 = 0; k0 < 512; k0 += 32) {
      __syncthreads();  // protect Abuf/Bbuf from previous iteration's readers
      stage16(&Abuf[r_st * 32 + kk_st], Asrc + k0);
      stage16(&Bbuf[r_st * 32 + kk_st], Bsrc + k0);
      __syncthreads();
      s16x8 af[4], bfr[4];
#pragma unroll
      for (int i = 0; i < 4; ++i)
        af[i] = *reinterpret_cast<const s16x8*>(&Abuf[(wr + i * 16 + l16) * 32 + quad * 8]);
#pragma unroll
      for (int j = 0; j < 4; ++j)
        bfr[j] = *reinterpret_cast<const s16x8*>(&Bbuf[(wc + j * 16 + l16) * 32 + quad * 8]);
#pragma unroll
      for (int i = 0; i < 4; ++i)
#pragma unroll
        for (int j = 0; j < 4; ++j) acc[i][j] = mfma16(af[i], bfr[j], acc[i][j]);
    }

    float bias[4];
#pragma unroll
    for (int j = 0; j < 4; ++j) bias[j] = tofl(bkv[nc0 + wc + j * 16 + l16]);

    // spill accumulator (+bias) to kvbuf as bf16.
    // K phase: [s][c] (u-GEMM B-operand wants contiguous d per fixed s)
    // V phase: [c][s] transposed (num-GEMM B-operand wants contiguous s per fixed d)
#pragma unroll
    for (int i = 0; i < 4; ++i)
#pragma unroll
      for (int j = 0; j < 4; ++j)
#pragma unroll
        for (int rg = 0; rg < 4; ++rg) {
          int sl = wr + i * 16 + quad * 4 + rg;  // D row = s-row
          int c = wc + j * 16 + l16;             // D col = kv col (local)
          unsigned short bv = f2bf(acc[i][j][rg] + bias[j]);
          if (phase == 0)
            kvbuf[sl * 128 + c] = bv;
          else
            kvbuf[c * 128 + sl] = bv;
        }
    __syncthreads();  // spill visible to all waves

    if (phase == 0) {
      // ---- u-GEMM: u[q=32][s=128] per head; wave (hh,mt) does 16 q rows ----
      f32x4 ua[8];
#pragma unroll
      for (int j = 0; j < 8; ++j) ua[j] = zero4;
#pragma unroll
      for (int kk = 0; kk < 2; ++kk) {
        // A-operand from q scratch (bf16): m = q row, k = d
        s16x8 aq = *reinterpret_cast<const s16x8*>(
            qws + ((size_t)(b * 32 + mt * 16 + l16)) * 512 + hp * 128 + hh * 64 + kk * 32 +
            quad * 8);
#pragma unroll
        for (int j = 0; j < 8; ++j) {
          // B-operand: n = s (row of kvbuf), k = d contiguous
          s16x8 bk = *reinterpret_cast<const s16x8*>(
              &kvbuf[(j * 16 + l16) * 128 + hh * 64 + kk * 32 + quad * 8]);
          ua[j] = mfma16(aq, bk, ua[j]);
        }
      }
      const float scale = 0.044194173824159216f;  // 1/sqrt(512)
#pragma unroll
      for (int j = 0; j < 8; ++j) {
        int scol = j * 16 + l16;
        float mask = tofl(masks[(size_t)b * 4096 + s0 + scol]);
#pragma unroll
        for (int rg = 0; rg < 4; ++rg) {
          int qrow = mt * 16 + quad * 4 + rg;
          float uv = ua[j][rg] * scale;
          float e = uv > 0.f ? uv : expm1f(uv);  // elu
          e = fminf(fmaxf(e, -15.f), 15.f);      // clip
          float p = expf(e) * mask;
          Pbuf[(hh * 32 + qrow) * 128 + scol] = f2bf(p);
        }
      }
      __syncthreads();
      // ---- den partial: sum P over this s-tile, atomic to global ----
      if (tid < 64) {
        int h2 = tid >> 5, q = tid & 31;
        float s = 0.f;
        for (int sc = 0; sc < 128; ++sc) s += bf2f(Pbuf[(h2 * 32 + q) * 128 + sc]);
        atomicAdd(&den[((size_t)b * 32 + q) * 8 + hp * 2 + h2], s);
      }
      // next phase's k-loop top __syncthreads() covers Pbuf/den readers
    } else {
      // ---- num-GEMM: num[q=32][d=64] += P(32x128) @ V(128x64) per head ----
      f32x4 na[4];
#pragma unroll
      for (int j = 0; j < 4; ++j) na[j] = zero4;
#pragma unroll
      for (int kk = 0; kk < 4; ++kk) {
        // A-operand = P: m = q row, k = s contiguous
        s16x8 ap = *reinterpret_cast<const s16x8*>(
            &Pbuf[(hh * 32 + mt * 16 + l16) * 128 + kk * 32 + quad * 8]);
#pragma unroll
        for (int j = 0; j < 4; ++j) {
          // B-operand = V^T rows: n = d, k = s contiguous (kvbuf transposed)
          s16x8 bv = *reinterpret_cast<const s16x8*>(
              &kvbuf[(hh * 64 + j * 16 + l16) * 128 + kk * 32 + quad * 8]);
          na[j] = mfma16(ap, bv, na[j]);
        }
      }
      const int h = hp * 2 + hh;
#pragma unroll
      for (int j = 0; j < 4; ++j)
#pragma unroll
        for (int rg = 0; rg < 4; ++rg) {
          int qrow = mt * 16 + quad * 4 + rg;
          int d = j * 16 + l16;
          atomicAdd(&num[(((size_t)b * 32 + qrow) * 8 + h) * 64 + d], na[j][rg]);
        }
    }
  }
}

__global__ __launch_bounds__(256) void k_fused(const void* inputs, const void* masks,
                                               const void* Wkv, const void* bkv,
                                               const unsigned short* __restrict__ qws,
                                               float* __restrict__ num,
                                               float* __restrict__ den,
                                               const int* __restrict__ flag) {
  // exactly 64 KiB of LDS
  __shared__ unsigned short Abuf[128 * 32];    // inputs tile [s][k]   8 KiB
  __shared__ unsigned short Bbuf[128 * 32];    // Wkv tile [n][k]      8 KiB
  __shared__ unsigned short kvbuf[128 * 128];  // K:[s][c] / V:[c][s] 32 KiB
  __shared__ unsigned short Pbuf[2 * 32 * 128];// [hh][q][s]          16 KiB
  if (*flag == 1)
    fused_body<float>((const float*)inputs, (const float*)masks, (const float*)Wkv,
                      (const float*)bkv, qws, num, den, Abuf, Bbuf, kvbuf, Pbuf);
  else
    fused_body<__hip_bfloat16>((const __hip_bfloat16*)inputs, (const __hip_bfloat16*)masks,
                               (const __hip_bfloat16*)Wkv, (const __hip_bfloat16*)bkv, qws,
                               num, den, Abuf, Bbuf, kvbuf, Pbuf);
}

// ---------------------------------------------------------------------------
// final divide: out[b,q,h*64+d] = num / den   (flat index identical)
// ---------------------------------------------------------------------------
__global__ __launch_bounds__(256) void k_div(const float* __restrict__ num,
                                             const float* __restrict__ den, void* out,
                                             const int* __restrict__ flag) {
  int i = blockIdx.x * 256 + threadIdx.x;
  float v = num[i] / den[i >> 6];
  if (*flag == 1)
    ((float*)out)[i] = v;
  else
    ((__hip_bfloat16*)out)[i] = __float2bfloat16(v);
}

// ---------------------------------------------------------------------------
extern "C" void kernel_launch(void* const* d_in, const int* in_sizes, int n_in,
                              void* d_out, int out_size, void* d_ws, size_t ws_size,
                              hipStream_t stream) {
  // d_in: 0 inputs, 1 queries, 2 masks, 3 Wkv, 4 bkv, 5 Wq, 6 bq
  // ws layout: [0] flag(int) ; [1024] den 2048 f32 ; [16384] num 131072 f32 ;
  //            [540672] qws 131072 u16  -> total 802816 bytes
  if (ws_size < 802816) return;  // fail loudly (output stays poisoned)
  char* ws = (char*)d_ws;
  int* flag = (int*)ws;
  float* den = (float*)(ws + 1024);
  float* num = (float*)(ws + 16384);
  unsigned short* qws = (unsigned short*)(ws + 540672);

  // zero flag + den + num in one shot
  hipMemsetAsync(d_ws, 0, 540672, stream);

  k_detect<<<1, 256, 0, stream>>>((const unsigned short*)d_in[0], flag);

  k_qproj<<<128, 256, 0, stream>>>(d_in[1], d_in[5], d_in[6], qws, flag);

  dim3 g2(32, 8, 4);
  k_fused<<<g2, 256, 0, stream>>>(d_in[0], d_in[2], d_in[3], d_in[4], qws, num, den, flag);

  k_div<<<512, 256, 0, stream>>>(num, den, d_out, flag);
}

// Round 3
// 284.508 us; speedup vs baseline: 1.2237x; 1.2237x over previous
//
#include <hip/hip_runtime.h>
#include <hip/hip_bf16.h>

// ---------------------------------------------------------------------------
// MultiHeadAttention fused kernel for MI355X (gfx950)
// B=8 S=4096 Q=32 H=8 D=64 IN=512 NKV=1024
// detect dtype -> q projection -> fused (KV-proj + attention partials via
// atomics) -> divide.
// R3: reg-prefetch pipelined K-loop, XOR-swizzled kvbuf/Pbuf (bank conflicts),
//     shuffle-based den reduction, vectorized 256-block qproj.
// ---------------------------------------------------------------------------

typedef float f32x4 __attribute__((ext_vector_type(4)));
typedef short s16x8 __attribute__((ext_vector_type(8)));

__device__ __forceinline__ unsigned short f2bf(float f) {
  union { __hip_bfloat16 h; unsigned short u; } cv;
  cv.h = __float2bfloat16(f);
  return cv.u;
}
__device__ __forceinline__ float bf2f(unsigned short u) {
  union { unsigned short u; __hip_bfloat16 h; } cv;
  cv.u = u;
  return __bfloat162float(cv.h);
}
__device__ __forceinline__ float tofl(float v) { return v; }
__device__ __forceinline__ float tofl(__hip_bfloat16 v) { return __bfloat162float(v); }

__device__ __forceinline__ f32x4 mfma16(s16x8 a, s16x8 b, f32x4 c) {
  return __builtin_amdgcn_mfma_f32_16x16x32_bf16(a, b, c, 0, 0, 0);
}

// XOR swizzle in 8-u16 (16 B) blocks: row-major [r][128] with col-block
// permuted by (r&7). Bijective per row; spreads fragment reads whose lane
// index varies the ROW (stride 256 B = bank-aligned) across all 32 banks.
__device__ __forceinline__ int kv_idx(int r, int c) {
  return r * 128 + ((((c >> 3) ^ (r & 7)) << 3) | (c & 7));
}
__device__ __forceinline__ int p_idx(int r, int c) {
  return r * 128 + ((((c >> 3) ^ (r & 7)) << 3) | (c & 7));
}

// 16-element (along K) register chunk, stored to LDS as bf16
template <typename T> struct RegChunk;
template <> struct RegChunk<float> {
  float4 v[4];
  __device__ __forceinline__ void load(const float* p) {
    const float4* q = reinterpret_cast<const float4*>(p);
    v[0] = q[0]; v[1] = q[1]; v[2] = q[2]; v[3] = q[3];
  }
  __device__ __forceinline__ void store(unsigned short* d) {
    union { unsigned short u[16]; s16x8 w[2]; } t;
    const float* f = reinterpret_cast<const float*>(v);
#pragma unroll
    for (int i = 0; i < 16; ++i) t.u[i] = f2bf(f[i]);
    reinterpret_cast<s16x8*>(d)[0] = t.w[0];
    reinterpret_cast<s16x8*>(d)[1] = t.w[1];
  }
};
template <> struct RegChunk<__hip_bfloat16> {
  s16x8 v[2];
  __device__ __forceinline__ void load(const __hip_bfloat16* p) {
    const s16x8* q = reinterpret_cast<const s16x8*>(p);
    v[0] = q[0]; v[1] = q[1];
  }
  __device__ __forceinline__ void store(unsigned short* d) {
    reinterpret_cast<s16x8*>(d)[0] = v[0];
    reinterpret_cast<s16x8*>(d)[1] = v[1];
  }
};

// ---------------------------------------------------------------------------
// dtype detection: EVEN u16 entries. bf16 array -> real bf16 values
// (plausible exponent ~100%); fp32 array (LE) -> mantissa low halves (~12%).
// flag: 1 = fp32, 0 = bf16.
// ---------------------------------------------------------------------------
__global__ void k_detect(const unsigned short* __restrict__ in16, int* __restrict__ flag) {
  __shared__ int cnt;
  int t = threadIdx.x;
  if (t == 0) cnt = 0;
  __syncthreads();
  unsigned short v = in16[2 * t];
  int e = (v >> 7) & 0xFF;
  int ok = (e >= 100 && e <= 130) ? 1 : 0;
  atomicAdd(&cnt, ok);
  __syncthreads();
  if (t == 0) *flag = (cnt >= 128) ? 0 : 1;
}

// ---------------------------------------------------------------------------
// q projection: one block per output row (256 rows), thread t -> cols t,t+256.
// float path vectorized float4; Wq rows are L2-resident (1 MB) with full
// 64B-line reuse per thread across k.
// ---------------------------------------------------------------------------
template <typename T>
__device__ __forceinline__ void qproj_body(const T* __restrict__ queries,
                                           const T* __restrict__ Wq,
                                           const T* __restrict__ bq,
                                           unsigned short* __restrict__ qws,
                                           float* qrow /* 512 LDS */) {
  const int r = blockIdx.x;  // 0..255 = b*32+q
  const int t = threadIdx.x;
  if constexpr (sizeof(T) == 4) {
    if (t < 128) {
      reinterpret_cast<float4*>(qrow)[t] =
          reinterpret_cast<const float4*>(queries + (size_t)r * 512)[t];
    }
  } else {
    for (int i = t; i < 512; i += 256) qrow[i] = tofl(queries[(size_t)r * 512 + i]);
  }
  __syncthreads();
  const int c0 = t, c1 = t + 256;
  float a0 = 0.f, a1 = 0.f;
  if constexpr (sizeof(T) == 4) {
    const float4* w0 = reinterpret_cast<const float4*>(Wq + (size_t)c0 * 512);
    const float4* w1 = reinterpret_cast<const float4*>(Wq + (size_t)c1 * 512);
    const float4* q4 = reinterpret_cast<const float4*>(qrow);
#pragma unroll 4
    for (int k = 0; k < 128; ++k) {
      float4 qv = q4[k];
      float4 x = w0[k], y = w1[k];
      a0 += qv.x * x.x + qv.y * x.y + qv.z * x.z + qv.w * x.w;
      a1 += qv.x * y.x + qv.y * y.y + qv.z * y.z + qv.w * y.w;
    }
  } else {
    const T* w0 = Wq + (size_t)c0 * 512;
    const T* w1 = Wq + (size_t)c1 * 512;
    for (int k = 0; k < 512; ++k) {
      a0 += qrow[k] * tofl(w0[k]);
      a1 += qrow[k] * tofl(w1[k]);
    }
  }
  qws[(size_t)r * 512 + c0] = f2bf(a0 + tofl(bq[c0]));
  qws[(size_t)r * 512 + c1] = f2bf(a1 + tofl(bq[c1]));
}

__global__ __launch_bounds__(256) void k_qproj(const void* queries, const void* Wq,
                                               const void* bq, unsigned short* qws,
                                               const int* __restrict__ flag) {
  __shared__ float qrow[512];
  if (*flag == 1)
    qproj_body<float>((const float*)queries, (const float*)Wq, (const float*)bq, qws, qrow);
  else
    qproj_body<__hip_bfloat16>((const __hip_bfloat16*)queries, (const __hip_bfloat16*)Wq,
                               (const __hip_bfloat16*)bq, qws, qrow);
}

// ---------------------------------------------------------------------------
// Fused kernel. Grid (32 s-tiles, 8 batches, 4 head-pairs), 256 threads.
// MFMA 16x16x32_bf16 layouts (HW-verified):
//   A: m=lane&15, k=quad*8+j ; B: n=lane&15, k=quad*8+j ;
//   D: col=lane&15, row=quad*4+reg
// ---------------------------------------------------------------------------
template <typename T>
__device__ __forceinline__ void fused_body(
    const T* __restrict__ inputs, const T* __restrict__ masks,
    const T* __restrict__ Wkv, const T* __restrict__ bkv,
    const unsigned short* __restrict__ qws,
    float* __restrict__ num, float* __restrict__ den,
    unsigned short* Abuf, unsigned short* Bbuf,
    unsigned short* kvbuf, unsigned short* Pbuf) {
  const int stile = blockIdx.x;  // 0..31
  const int b = blockIdx.y;      // 0..7
  const int hp = blockIdx.z;     // 0..3
  const int s0 = stile * 128;
  const int tid = threadIdx.x;
  const int w = tid >> 6;
  const int l = tid & 63;
  const int quad = l >> 4;
  const int l16 = l & 15;
  const int wr = (w >> 1) * 64;
  const int wc = (w & 1) * 64;
  const int hh = w >> 1;
  const int mt = w & 1;

  const int r_st = tid >> 1;
  const int kk_st = (tid & 1) * 16;
  const T* Asrc = inputs + ((size_t)(b * 4096 + s0 + r_st)) * 512 + kk_st;

  const f32x4 zero4 = {0.f, 0.f, 0.f, 0.f};

  for (int phase = 0; phase < 2; ++phase) {
    const int nc0 = phase * 512 + hp * 128;
    f32x4 acc[4][4];
#pragma unroll
    for (int i = 0; i < 4; ++i)
#pragma unroll
      for (int j = 0; j < 4; ++j) acc[i][j] = zero4;

    const T* Bsrc = Wkv + ((size_t)(nc0 + r_st)) * 512 + kk_st;

    // ---- pipelined K-loop: prefetch chunk k+1 into regs during MFMA of k ----
    RegChunk<T> ra, rb;
    ra.load(Asrc);
    rb.load(Bsrc);
    for (int k0 = 0; k0 < 512; k0 += 32) {
      __syncthreads();  // staging buffers safe to overwrite
      ra.store(&Abuf[r_st * 32 + kk_st]);
      rb.store(&Bbuf[r_st * 32 + kk_st]);
      if (k0 + 32 < 512) {       // issue next chunk's loads; consumed next iter
        ra.load(Asrc + k0 + 32); // -> latency overlapped by barrier+frags+MFMA
        rb.load(Bsrc + k0 + 32);
      }
      __syncthreads();  // staging visible
      s16x8 af[4], bfr[4];
#pragma unroll
      for (int i = 0; i < 4; ++i)
        af[i] = *reinterpret_cast<const s16x8*>(&Abuf[(wr + i * 16 + l16) * 32 + quad * 8]);
#pragma unroll
      for (int j = 0; j < 4; ++j)
        bfr[j] = *reinterpret_cast<const s16x8*>(&Bbuf[(wc + j * 16 + l16) * 32 + quad * 8]);
#pragma unroll
      for (int i = 0; i < 4; ++i)
#pragma unroll
        for (int j = 0; j < 4; ++j) acc[i][j] = mfma16(af[i], bfr[j], acc[i][j]);
    }

    float bias[4];
#pragma unroll
    for (int j = 0; j < 4; ++j) bias[j] = tofl(bkv[nc0 + wc + j * 16 + l16]);

    // spill acc(+bias) to kvbuf as bf16 (swizzled).
    // K phase: [s][c]; V phase: [c][s] transposed.
#pragma unroll
    for (int i = 0; i < 4; ++i)
#pragma unroll
      for (int j = 0; j < 4; ++j)
#pragma unroll
        for (int rg = 0; rg < 4; ++rg) {
          int sl = wr + i * 16 + quad * 4 + rg;
          int c = wc + j * 16 + l16;
          unsigned short bv = f2bf(acc[i][j][rg] + bias[j]);
          if (phase == 0)
            kvbuf[kv_idx(sl, c)] = bv;
          else
            kvbuf[kv_idx(c, sl)] = bv;
        }
    __syncthreads();

    if (phase == 0) {
      // ---- u-GEMM: u[q=32][s=128] per head; wave (hh,mt) -> 16 q rows ----
      f32x4 ua[8];
#pragma unroll
      for (int j = 0; j < 8; ++j) ua[j] = zero4;
#pragma unroll
      for (int kk = 0; kk < 2; ++kk) {
        s16x8 aq = *reinterpret_cast<const s16x8*>(
            qws + ((size_t)(b * 32 + mt * 16 + l16)) * 512 + hp * 128 + hh * 64 + kk * 32 +
            quad * 8);
#pragma unroll
        for (int j = 0; j < 8; ++j) {
          s16x8 bk = *reinterpret_cast<const s16x8*>(
              &kvbuf[kv_idx(j * 16 + l16, hh * 64 + kk * 32 + quad * 8)]);
          ua[j] = mfma16(aq, bk, ua[j]);
        }
      }
      const float scale = 0.044194173824159216f;  // 1/sqrt(512)
      float dsum[4] = {0.f, 0.f, 0.f, 0.f};
#pragma unroll
      for (int j = 0; j < 8; ++j) {
        int scol = j * 16 + l16;
        float mask = tofl(masks[(size_t)b * 4096 + s0 + scol]);
#pragma unroll
        for (int rg = 0; rg < 4; ++rg) {
          int qrow = mt * 16 + quad * 4 + rg;
          float uv = ua[j][rg] * scale;
          float e = uv > 0.f ? uv : expm1f(uv);
          e = fminf(fmaxf(e, -15.f), 15.f);
          float p = expf(e) * mask;
          unsigned short pu = f2bf(p);
          Pbuf[p_idx(hh * 32 + qrow, scol)] = pu;
          dsum[rg] += bf2f(pu);  // sum the ROUNDED value num-GEMM will use
        }
      }
      // ---- den: shuffle-reduce over the 16 lanes of each quad ----
#pragma unroll
      for (int rg = 0; rg < 4; ++rg) {
        float s = dsum[rg];
        s += __shfl_xor(s, 1);
        s += __shfl_xor(s, 2);
        s += __shfl_xor(s, 4);
        s += __shfl_xor(s, 8);
        if (l16 == 0) {
          int qrow = mt * 16 + quad * 4 + rg;
          atomicAdd(&den[((size_t)(b * 32 + qrow)) * 8 + hp * 2 + hh], s);
        }
      }
      // phase-1 k-loop top barrier orders Pbuf/kvbuf reuse
    } else {
      // ---- num-GEMM: num[q=32][d=64] += P(32x128) @ V(128x64) per head ----
      f32x4 na[4];
#pragma unroll
      for (int j = 0; j < 4; ++j) na[j] = zero4;
#pragma unroll
      for (int kk = 0; kk < 4; ++kk) {
        s16x8 ap = *reinterpret_cast<const s16x8*>(
            &Pbuf[p_idx(hh * 32 + mt * 16 + l16, kk * 32 + quad * 8)]);
#pragma unroll
        for (int j = 0; j < 4; ++j) {
          s16x8 bv = *reinterpret_cast<const s16x8*>(
              &kvbuf[kv_idx(hh * 64 + j * 16 + l16, kk * 32 + quad * 8)]);
          na[j] = mfma16(ap, bv, na[j]);
        }
      }
      const int h = hp * 2 + hh;
#pragma unroll
      for (int j = 0; j < 4; ++j)
#pragma unroll
        for (int rg = 0; rg < 4; ++rg) {
          int qrow = mt * 16 + quad * 4 + rg;
          int d = j * 16 + l16;
          atomicAdd(&num[(((size_t)(b * 32 + qrow)) * 8 + h) * 64 + d], na[j][rg]);
        }
    }
  }
}

__global__ __launch_bounds__(256) void k_fused(const void* inputs, const void* masks,
                                               const void* Wkv, const void* bkv,
                                               const unsigned short* __restrict__ qws,
                                               float* __restrict__ num,
                                               float* __restrict__ den,
                                               const int* __restrict__ flag) {
  __shared__ unsigned short Abuf[128 * 32];     // 8 KiB
  __shared__ unsigned short Bbuf[128 * 32];     // 8 KiB
  __shared__ unsigned short kvbuf[128 * 128];   // 32 KiB (swizzled)
  __shared__ unsigned short Pbuf[2 * 32 * 128]; // 16 KiB (swizzled)
  if (*flag == 1)
    fused_body<float>((const float*)inputs, (const float*)masks, (const float*)Wkv,
                      (const float*)bkv, qws, num, den, Abuf, Bbuf, kvbuf, Pbuf);
  else
    fused_body<__hip_bfloat16>((const __hip_bfloat16*)inputs, (const __hip_bfloat16*)masks,
                               (const __hip_bfloat16*)Wkv, (const __hip_bfloat16*)bkv, qws,
                               num, den, Abuf, Bbuf, kvbuf, Pbuf);
}

// ---------------------------------------------------------------------------
__global__ __launch_bounds__(256) void k_div(const float* __restrict__ num,
                                             const float* __restrict__ den, void* out,
                                             const int* __restrict__ flag) {
  int i = blockIdx.x * 256 + threadIdx.x;
  float v = num[i] / den[i >> 6];
  if (*flag == 1)
    ((float*)out)[i] = v;
  else
    ((__hip_bfloat16*)out)[i] = __float2bfloat16(v);
}

// ---------------------------------------------------------------------------
extern "C" void kernel_launch(void* const* d_in, const int* in_sizes, int n_in,
                              void* d_out, int out_size, void* d_ws, size_t ws_size,
                              hipStream_t stream) {
  // d_in: 0 inputs, 1 queries, 2 masks, 3 Wkv, 4 bkv, 5 Wq, 6 bq
  // ws: [0] flag ; [1024] den 2048 f32 ; [16384] num 131072 f32 ;
  //     [540672] qws 131072 u16 -> 802816 bytes
  if (ws_size < 802816) return;
  char* ws = (char*)d_ws;
  int* flag = (int*)ws;
  float* den = (float*)(ws + 1024);
  float* num = (float*)(ws + 16384);
  unsigned short* qws = (unsigned short*)(ws + 540672);

  hipMemsetAsync(d_ws, 0, 540672, stream);

  k_detect<<<1, 256, 0, stream>>>((const unsigned short*)d_in[0], flag);

  k_qproj<<<256, 256, 0, stream>>>(d_in[1], d_in[5], d_in[6], qws, flag);

  dim3 g2(32, 8, 4);
  k_fused<<<g2, 256, 0, stream>>>(d_in[0], d_in[2], d_in[3], d_in[4], qws, num, den, flag);

  k_div<<<512, 256, 0, stream>>>(num, den, d_out, flag);
}

// Round 4
// 242.137 us; speedup vs baseline: 1.4378x; 1.1750x over previous
//
#include <hip/hip_runtime.h>
#include <hip/hip_bf16.h>

// ---------------------------------------------------------------------------
// MultiHeadAttention fused kernel for MI355X (gfx950)
// B=8 S=4096 Q=32 H=8 D=64 IN=512 NKV=1024
// detect dtype -> q projection (MFMA) -> fused (merged K+V proj in ONE K-loop
// + attention partials via atomics) -> divide.
// R4: 512-thr blocks (2 waves/SIMD), merged K/V K-loop (half barriers, half
//     A-traffic), MFMA qproj.
// ---------------------------------------------------------------------------

typedef float f32x4 __attribute__((ext_vector_type(4)));
typedef short s16x8 __attribute__((ext_vector_type(8)));

__device__ __forceinline__ unsigned short f2bf(float f) {
  union { __hip_bfloat16 h; unsigned short u; } cv;
  cv.h = __float2bfloat16(f);
  return cv.u;
}
__device__ __forceinline__ float bf2f(unsigned short u) {
  union { unsigned short u; __hip_bfloat16 h; } cv;
  cv.u = u;
  return __bfloat162float(cv.h);
}
__device__ __forceinline__ float tofl(float v) { return v; }
__device__ __forceinline__ float tofl(__hip_bfloat16 v) { return __bfloat162float(v); }

__device__ __forceinline__ f32x4 mfma16(s16x8 a, s16x8 b, f32x4 c) {
  return __builtin_amdgcn_mfma_f32_16x16x32_bf16(a, b, c, 0, 0, 0);
}

// XOR swizzle in 8-u16 (16 B) blocks over a 128-col row: breaks the 256 B
// (bank-aligned) row stride for fragment reads / transposed spills.
__device__ __forceinline__ int sw_idx(int r, int c) {
  return r * 128 + ((((c >> 3) ^ (r & 7)) << 3) | (c & 7));
}

// 16-element (along K) register chunk, stored to LDS as bf16
template <typename T> struct RegChunk;
template <> struct RegChunk<float> {
  float4 v[4];
  __device__ __forceinline__ void load(const float* p) {
    const float4* q = reinterpret_cast<const float4*>(p);
    v[0] = q[0]; v[1] = q[1]; v[2] = q[2]; v[3] = q[3];
  }
  __device__ __forceinline__ void store(unsigned short* d) {
    union { unsigned short u[16]; s16x8 w[2]; } t;
    const float* f = reinterpret_cast<const float*>(v);
#pragma unroll
    for (int i = 0; i < 16; ++i) t.u[i] = f2bf(f[i]);
    reinterpret_cast<s16x8*>(d)[0] = t.w[0];
    reinterpret_cast<s16x8*>(d)[1] = t.w[1];
  }
};
template <> struct RegChunk<__hip_bfloat16> {
  s16x8 v[2];
  __device__ __forceinline__ void load(const __hip_bfloat16* p) {
    const s16x8* q = reinterpret_cast<const s16x8*>(p);
    v[0] = q[0]; v[1] = q[1];
  }
  __device__ __forceinline__ void store(unsigned short* d) {
    reinterpret_cast<s16x8*>(d)[0] = v[0];
    reinterpret_cast<s16x8*>(d)[1] = v[1];
  }
};

// ---------------------------------------------------------------------------
// dtype detection: EVEN u16 entries. bf16 array -> real bf16 values
// (plausible exponent ~100%); fp32 array (LE) -> mantissa low halves (~12%).
// flag: 1 = fp32, 0 = bf16.
// ---------------------------------------------------------------------------
__global__ void k_detect(const unsigned short* __restrict__ in16, int* __restrict__ flag) {
  __shared__ int cnt;
  int t = threadIdx.x;
  if (t == 0) cnt = 0;
  __syncthreads();
  unsigned short v = in16[2 * t];
  int e = (v >> 7) & 0xFF;
  int ok = (e >= 100 && e <= 130) ? 1 : 0;
  atomicAdd(&cnt, ok);
  __syncthreads();
  if (t == 0) *flag = (cnt >= 128) ? 0 : 1;
}

// ---------------------------------------------------------------------------
// q projection as MFMA GEMM: qws[256][512] = queries[256][512] @ Wq^T + bq
// grid (2 Mtiles, 4 Ntiles), 256 thr, 128x128 tile, BK=32.
// MFMA 16x16x32_bf16 layouts (HW-verified):
//   A: m=lane&15, k=quad*8+j ; B: n=lane&15, k=quad*8+j ;
//   D: col=lane&15, row=quad*4+reg
// ---------------------------------------------------------------------------
template <typename T>
__device__ __forceinline__ void qproj_body(const T* __restrict__ queries,
                                           const T* __restrict__ Wq,
                                           const T* __restrict__ bq,
                                           unsigned short* __restrict__ qws,
                                           unsigned short* Abuf, unsigned short* Bbuf) {
  const int Mt = blockIdx.x, Nt = blockIdx.y;
  const int tid = threadIdx.x;
  const int w = tid >> 6, l = tid & 63;
  const int quad = l >> 4, l16 = l & 15;
  const int wr = (w >> 1) * 64, wc = (w & 1) * 64;

  const int r_st = tid >> 1;
  const int kk_st = (tid & 1) * 16;
  const T* Asrc = queries + ((size_t)(Mt * 128 + r_st)) * 512 + kk_st;
  const T* Bsrc = Wq + ((size_t)(Nt * 128 + r_st)) * 512 + kk_st;

  const f32x4 zero4 = {0.f, 0.f, 0.f, 0.f};
  f32x4 acc[4][4];
#pragma unroll
  for (int i = 0; i < 4; ++i)
#pragma unroll
    for (int j = 0; j < 4; ++j) acc[i][j] = zero4;

  RegChunk<T> ra, rb;
  ra.load(Asrc);
  rb.load(Bsrc);
  for (int k0 = 0; k0 < 512; k0 += 32) {
    __syncthreads();
    ra.store(&Abuf[r_st * 32 + kk_st]);
    rb.store(&Bbuf[r_st * 32 + kk_st]);
    if (k0 + 32 < 512) {
      ra.load(Asrc + k0 + 32);
      rb.load(Bsrc + k0 + 32);
    }
    __syncthreads();
    s16x8 af[4], bfr[4];
#pragma unroll
    for (int i = 0; i < 4; ++i)
      af[i] = *reinterpret_cast<const s16x8*>(&Abuf[(wr + i * 16 + l16) * 32 + quad * 8]);
#pragma unroll
    for (int j = 0; j < 4; ++j)
      bfr[j] = *reinterpret_cast<const s16x8*>(&Bbuf[(wc + j * 16 + l16) * 32 + quad * 8]);
#pragma unroll
    for (int i = 0; i < 4; ++i)
#pragma unroll
      for (int j = 0; j < 4; ++j) acc[i][j] = mfma16(af[i], bfr[j], acc[i][j]);
  }

#pragma unroll
  for (int j = 0; j < 4; ++j) {
    float bb = tofl(bq[Nt * 128 + wc + j * 16 + l16]);
#pragma unroll
    for (int i = 0; i < 4; ++i)
#pragma unroll
      for (int rg = 0; rg < 4; ++rg) {
        int row = Mt * 128 + wr + i * 16 + quad * 4 + rg;
        int col = Nt * 128 + wc + j * 16 + l16;
        qws[(size_t)row * 512 + col] = f2bf(acc[i][j][rg] + bb);
      }
  }
}

__global__ __launch_bounds__(256) void k_qproj(const void* queries, const void* Wq,
                                               const void* bq, unsigned short* qws,
                                               const int* __restrict__ flag) {
  __shared__ unsigned short Abuf[128 * 32];
  __shared__ unsigned short Bbuf[128 * 32];
  if (*flag == 1)
    qproj_body<float>((const float*)queries, (const float*)Wq, (const float*)bq, qws, Abuf,
                      Bbuf);
  else
    qproj_body<__hip_bfloat16>((const __hip_bfloat16*)queries, (const __hip_bfloat16*)Wq,
                               (const __hip_bfloat16*)bq, qws, Abuf, Bbuf);
}

// ---------------------------------------------------------------------------
// Fused kernel. Grid (32 s-tiles, 8 batches, 4 head-pairs), 512 threads
// (8 waves). ONE K-loop computes both K-block (128x128) and V-block (128x128)
// of the head-pair: waves 0-3 own K-output quadrants (and stage A), waves 4-7
// own V-output quadrants (and stage the 256-row B). Then u-GEMM -> P -> den,
// num-GEMM -> atomics.
// ---------------------------------------------------------------------------
template <typename T>
__device__ __forceinline__ void fused_body(
    const T* __restrict__ inputs, const T* __restrict__ masks,
    const T* __restrict__ Wkv, const T* __restrict__ bkv,
    const unsigned short* __restrict__ qws,
    float* __restrict__ num, float* __restrict__ den,
    unsigned short* Abuf, unsigned short* Bbuf,
    unsigned short* kvbuf, unsigned short* vbuf, unsigned short* Pbuf) {
  const int stile = blockIdx.x;  // 0..31
  const int b = blockIdx.y;      // 0..7
  const int hp = blockIdx.z;     // 0..3
  const int s0 = stile * 128;
  const int tid = threadIdx.x;
  const int w = tid >> 6;        // 0..7
  const int l = tid & 63;
  const int quad = l >> 4;
  const int l16 = l & 15;
  // K-loop output mapping: which = 0 (K) for waves 0-3, 1 (V) for waves 4-7
  const int which = w >> 2;
  const int wr = ((w >> 1) & 1) * 64;
  const int wc = (w & 1) * 64;

  const f32x4 zero4 = {0.f, 0.f, 0.f, 0.f};
  f32x4 acc[4][4];
#pragma unroll
  for (int i = 0; i < 4; ++i)
#pragma unroll
    for (int j = 0; j < 4; ++j) acc[i][j] = zero4;

  // staging roles: tid<256 stage A (128x32), tid>=256 stage B (256x32)
  const int is_a = (tid < 256) ? 1 : 0;
  const int r_st = is_a ? (tid >> 1) : 0;         // A row 0..127
  const int kk_st = is_a ? ((tid & 1) * 16) : 0;  // A col half
  const int u_st = tid - 256;                     // B row 0..255
  const T* Asrc = inputs + ((size_t)(b * 4096 + s0 + r_st)) * 512 + kk_st;
  const int gr = (u_st < 128) ? (hp * 128 + u_st) : (512 + hp * 128 + (u_st - 128));
  const T* Bsrc = Wkv + ((size_t)(is_a ? 0 : gr)) * 512;

  RegChunk<T> ra, rb0, rb1;
  if (is_a) {
    ra.load(Asrc);
  } else {
    rb0.load(Bsrc);
    rb1.load(Bsrc + 16);
  }
  for (int k0 = 0; k0 < 512; k0 += 32) {
    __syncthreads();  // staging buffers safe to overwrite
    if (is_a) {
      ra.store(&Abuf[r_st * 32 + kk_st]);
    } else {
      rb0.store(&Bbuf[u_st * 32]);
      rb1.store(&Bbuf[u_st * 32 + 16]);
    }
    if (k0 + 32 < 512) {  // prefetch next chunk; consumed next iteration
      if (is_a) {
        ra.load(Asrc + k0 + 32);
      } else {
        rb0.load(Bsrc + k0 + 32);
        rb1.load(Bsrc + k0 + 48);
      }
    }
    __syncthreads();  // staging visible
    s16x8 af[4], bfr[4];
#pragma unroll
    for (int i = 0; i < 4; ++i)
      af[i] = *reinterpret_cast<const s16x8*>(&Abuf[(wr + i * 16 + l16) * 32 + quad * 8]);
#pragma unroll
    for (int j = 0; j < 4; ++j)
      bfr[j] = *reinterpret_cast<const s16x8*>(
          &Bbuf[(which * 128 + wc + j * 16 + l16) * 32 + quad * 8]);
#pragma unroll
    for (int i = 0; i < 4; ++i)
#pragma unroll
      for (int j = 0; j < 4; ++j) acc[i][j] = mfma16(af[i], bfr[j], acc[i][j]);
  }

  // spill acc(+bias) to kvbuf (K, [s][c]) / vbuf (V, [c][s] transposed)
#pragma unroll
  for (int j = 0; j < 4; ++j) {
    float bb = tofl(bkv[which * 512 + hp * 128 + wc + j * 16 + l16]);
#pragma unroll
    for (int i = 0; i < 4; ++i)
#pragma unroll
      for (int rg = 0; rg < 4; ++rg) {
        int sl = wr + i * 16 + quad * 4 + rg;  // s-row (local)
        int c = wc + j * 16 + l16;             // kv col (local, = d)
        unsigned short bv = f2bf(acc[i][j][rg] + bb);
        if (which == 0)
          kvbuf[sw_idx(sl, c)] = bv;
        else
          vbuf[sw_idx(c, sl)] = bv;
      }
  }
  __syncthreads();

  // ---- u-GEMM: u[2h][32q][128s]; wave -> (hh, mt, s-half) ----
  const int hh = w >> 2, mt = (w >> 1) & 1, sh = w & 1;
  {
    f32x4 ua[4];
#pragma unroll
    for (int j = 0; j < 4; ++j) ua[j] = zero4;
#pragma unroll
    for (int kk = 0; kk < 2; ++kk) {
      s16x8 aq = *reinterpret_cast<const s16x8*>(
          qws + ((size_t)(b * 32 + mt * 16 + l16)) * 512 + hp * 128 + hh * 64 + kk * 32 +
          quad * 8);
#pragma unroll
      for (int j = 0; j < 4; ++j) {
        s16x8 bk = *reinterpret_cast<const s16x8*>(
            &kvbuf[sw_idx(sh * 64 + j * 16 + l16, hh * 64 + kk * 32 + quad * 8)]);
        ua[j] = mfma16(aq, bk, ua[j]);
      }
    }
    const float scale = 0.044194173824159216f;  // 1/sqrt(512)
    float dsum[4] = {0.f, 0.f, 0.f, 0.f};
#pragma unroll
    for (int j = 0; j < 4; ++j) {
      int scol = sh * 64 + j * 16 + l16;
      float mask = tofl(masks[(size_t)b * 4096 + s0 + scol]);
#pragma unroll
      for (int rg = 0; rg < 4; ++rg) {
        int qrow = mt * 16 + quad * 4 + rg;
        float uv = ua[j][rg] * scale;
        float e = uv > 0.f ? uv : expm1f(uv);
        e = fminf(fmaxf(e, -15.f), 15.f);
        float p = expf(e) * mask;
        unsigned short pu = f2bf(p);
        Pbuf[sw_idx(hh * 32 + qrow, scol)] = pu;
        dsum[rg] += bf2f(pu);  // sum the ROUNDED value num-GEMM will use
      }
    }
    // den: shuffle-reduce the 16 lanes of each quad; both s-halves atomicAdd
#pragma unroll
    for (int rg = 0; rg < 4; ++rg) {
      float s = dsum[rg];
      s += __shfl_xor(s, 1);
      s += __shfl_xor(s, 2);
      s += __shfl_xor(s, 4);
      s += __shfl_xor(s, 8);
      if (l16 == 0) {
        int qrow = mt * 16 + quad * 4 + rg;
        atomicAdd(&den[((size_t)(b * 32 + qrow)) * 8 + hp * 2 + hh], s);
      }
    }
  }
  __syncthreads();  // Pbuf complete

  // ---- num-GEMM: num[2h][32q][64d]; wave -> (hh, mt, d-half) ----
  {
    const int dh = w & 1;
    f32x4 na[2];
    na[0] = zero4;
    na[1] = zero4;
#pragma unroll
    for (int kk = 0; kk < 4; ++kk) {
      s16x8 ap = *reinterpret_cast<const s16x8*>(
          &Pbuf[sw_idx(hh * 32 + mt * 16 + l16, kk * 32 + quad * 8)]);
#pragma unroll
      for (int jj = 0; jj < 2; ++jj) {
        int j = dh * 2 + jj;
        s16x8 bv = *reinterpret_cast<const s16x8*>(
            &vbuf[sw_idx(hh * 64 + j * 16 + l16, kk * 32 + quad * 8)]);
        na[jj] = mfma16(ap, bv, na[jj]);
      }
    }
    const int h = hp * 2 + hh;
#pragma unroll
    for (int jj = 0; jj < 2; ++jj) {
      int d = (dh * 2 + jj) * 16 + l16;
#pragma unroll
      for (int rg = 0; rg < 4; ++rg) {
        int qrow = mt * 16 + quad * 4 + rg;
        atomicAdd(&num[(((size_t)(b * 32 + qrow)) * 8 + h) * 64 + d], na[jj][rg]);
      }
    }
  }
}

__global__ __launch_bounds__(512, 2) void k_fused(const void* inputs, const void* masks,
                                                  const void* Wkv, const void* bkv,
                                                  const unsigned short* __restrict__ qws,
                                                  float* __restrict__ num,
                                                  float* __restrict__ den,
                                                  const int* __restrict__ flag) {
  __shared__ unsigned short Abuf[128 * 32];     //  8 KiB  inputs chunk [s][k]
  __shared__ unsigned short Bbuf[256 * 32];     // 16 KiB  Wkv chunk (K+V rows)
  __shared__ unsigned short kvbuf[128 * 128];   // 32 KiB  K [s][c] swizzled
  __shared__ unsigned short vbuf[128 * 128];    // 32 KiB  V [c][s] swizzled
  __shared__ unsigned short Pbuf[64 * 128];     // 16 KiB  P [2h*32q][s] swizzled
  if (*flag == 1)
    fused_body<float>((const float*)inputs, (const float*)masks, (const float*)Wkv,
                      (const float*)bkv, qws, num, den, Abuf, Bbuf, kvbuf, vbuf, Pbuf);
  else
    fused_body<__hip_bfloat16>((const __hip_bfloat16*)inputs, (const __hip_bfloat16*)masks,
                               (const __hip_bfloat16*)Wkv, (const __hip_bfloat16*)bkv, qws,
                               num, den, Abuf, Bbuf, kvbuf, vbuf, Pbuf);
}

// ---------------------------------------------------------------------------
__global__ __launch_bounds__(256) void k_div(const float* __restrict__ num,
                                             const float* __restrict__ den, void* out,
                                             const int* __restrict__ flag) {
  int i = blockIdx.x * 256 + threadIdx.x;
  float v = num[i] / den[i >> 6];
  if (*flag == 1)
    ((float*)out)[i] = v;
  else
    ((__hip_bfloat16*)out)[i] = __float2bfloat16(v);
}

// ---------------------------------------------------------------------------
extern "C" void kernel_launch(void* const* d_in, const int* in_sizes, int n_in,
                              void* d_out, int out_size, void* d_ws, size_t ws_size,
                              hipStream_t stream) {
  // d_in: 0 inputs, 1 queries, 2 masks, 3 Wkv, 4 bkv, 5 Wq, 6 bq
  // ws: [0] flag ; [1024] den 2048 f32 ; [16384] num 131072 f32 ;
  //     [540672] qws 131072 u16 -> 802816 bytes
  if (ws_size < 802816) return;
  char* ws = (char*)d_ws;
  int* flag = (int*)ws;
  float* den = (float*)(ws + 1024);
  float* num = (float*)(ws + 16384);
  unsigned short* qws = (unsigned short*)(ws + 540672);

  hipMemsetAsync(d_ws, 0, 540672, stream);

  k_detect<<<1, 256, 0, stream>>>((const unsigned short*)d_in[0], flag);

  dim3 gq(2, 4);
  k_qproj<<<gq, 256, 0, stream>>>(d_in[1], d_in[5], d_in[6], qws, flag);

  dim3 g2(32, 8, 4);
  k_fused<<<g2, 512, 0, stream>>>(d_in[0], d_in[2], d_in[3], d_in[4], qws, num, den, flag);

  k_div<<<512, 256, 0, stream>>>(num, den, d_out, flag);
}